// Round 1
// baseline (754.822 us; speedup 1.0000x reference)
//
#include <hip/hip_runtime.h>
#include <hip/hip_bf16.h>

#define H 8
#define HD 32
#define DD 256
#define NEG_SLOPE 0.2f

// ---------------- fp32 tiled GEMM: C[M,N] = A[M,K] @ B[K,N] (+bias, +relu) ----
enum { E_NONE = 0, E_BIAS_RELU = 1, E_BIAS = 2 };

#define TM 64
#define TN 64
#define TK 16

template <int EPI>
__global__ __launch_bounds__(256) void gemm_f32(const float* __restrict__ A,
                                                const float* __restrict__ B,
                                                const float* __restrict__ bias,
                                                float* __restrict__ C,
                                                int M, int N, int K) {
    __shared__ float As[TK][TM + 1];  // [k][m], padded
    __shared__ float Bs[TK][TN];      // [k][n]

    const int tid = threadIdx.x;
    const int tx = tid & 15;   // col group 0..15
    const int ty = tid >> 4;   // row group 0..15
    const int row0 = blockIdx.x * TM;
    const int col0 = blockIdx.y * TN;

    // A-load mapping: each thread loads float4 of one row
    const int a_r = tid >> 2;            // 0..63
    const int a_k = (tid & 3) * 4;       // 0,4,8,12
    // B-load mapping
    const int b_k = tid >> 4;            // 0..15
    const int b_c = (tid & 15) * 4;      // 0..60

    const int garow = row0 + a_r;
    const bool a_ok = (garow < M);

    float c[4][4] = {};

    for (int kk = 0; kk < K; kk += TK) {
        float4 av = a_ok ? *(const float4*)(A + (size_t)garow * K + kk + a_k)
                         : make_float4(0.f, 0.f, 0.f, 0.f);
        float4 bv = *(const float4*)(B + (size_t)(kk + b_k) * N + col0 + b_c);
        As[a_k + 0][a_r] = av.x;
        As[a_k + 1][a_r] = av.y;
        As[a_k + 2][a_r] = av.z;
        As[a_k + 3][a_r] = av.w;
        *(float4*)&Bs[b_k][b_c] = bv;
        __syncthreads();
#pragma unroll
        for (int k = 0; k < TK; k++) {
            float a0 = As[k][ty * 4 + 0], a1 = As[k][ty * 4 + 1];
            float a2 = As[k][ty * 4 + 2], a3 = As[k][ty * 4 + 3];
            float b0 = Bs[k][tx * 4 + 0], b1 = Bs[k][tx * 4 + 1];
            float b2 = Bs[k][tx * 4 + 2], b3 = Bs[k][tx * 4 + 3];
            c[0][0] += a0 * b0; c[0][1] += a0 * b1; c[0][2] += a0 * b2; c[0][3] += a0 * b3;
            c[1][0] += a1 * b0; c[1][1] += a1 * b1; c[1][2] += a1 * b2; c[1][3] += a1 * b3;
            c[2][0] += a2 * b0; c[2][1] += a2 * b1; c[2][2] += a2 * b2; c[2][3] += a2 * b3;
            c[3][0] += a3 * b0; c[3][1] += a3 * b1; c[3][2] += a3 * b2; c[3][3] += a3 * b3;
        }
        __syncthreads();
    }

#pragma unroll
    for (int i = 0; i < 4; i++) {
        int r = row0 + ty * 4 + i;
        if (r < M) {
            int cbase = col0 + tx * 4;
            float4 v = make_float4(c[i][0], c[i][1], c[i][2], c[i][3]);
            if (EPI != E_NONE) {
                float4 bb = *(const float4*)(bias + cbase);
                v.x += bb.x; v.y += bb.y; v.z += bb.z; v.w += bb.w;
            }
            if (EPI == E_BIAS_RELU) {
                v.x = fmaxf(v.x, 0.f); v.y = fmaxf(v.y, 0.f);
                v.z = fmaxf(v.z, 0.f); v.w = fmaxf(v.w, 0.f);
            }
            *(float4*)(C + (size_t)r * N + cbase) = v;
        }
    }
}

// ---------------- attention scores: a_src[n,h], a_dst[n,h] -------------------
__global__ void attn_scores(const float* __restrict__ xp,
                            const float* __restrict__ att_s,
                            const float* __restrict__ att_d,
                            float* __restrict__ a_src, float* __restrict__ a_dst,
                            int NH) {
    int i = blockIdx.x * blockDim.x + threadIdx.x;  // i = n*H + h
    if (i >= NH) return;
    int h = i & (H - 1);
    const float4* v = (const float4*)(xp + (size_t)i * HD);
    const float4* as = (const float4*)(att_s + h * HD);
    const float4* ad = (const float4*)(att_d + h * HD);
    float s1 = 0.f, s2 = 0.f;
#pragma unroll
    for (int j = 0; j < HD / 4; j++) {
        float4 xv = v[j], a = as[j], d = ad[j];
        s1 += xv.x * a.x + xv.y * a.y + xv.z * a.z + xv.w * a.w;
        s2 += xv.x * d.x + xv.y * d.y + xv.z * d.z + xv.w * d.w;
    }
    a_src[i] = s1;
    a_dst[i] = s2;
}

// ---------------- CSR build: histogram -> scan -> scatter --------------------
__global__ void hist_kernel(const int* __restrict__ ei, int* __restrict__ counts, int E) {
    int e = blockIdx.x * blockDim.x + threadIdx.x;
    if (e < E) atomicAdd(&counts[ei[E + e]], 1);
}

__global__ __launch_bounds__(1024) void scan_kernel(const int* __restrict__ counts,
                                                    int* __restrict__ row_ptr, int N) {
    __shared__ int wsum[16];
    __shared__ int s_carry;
    int tid = threadIdx.x;
    int lane = tid & 63;
    int w = tid >> 6;
    if (tid == 0) { s_carry = 0; row_ptr[0] = 0; }
    __syncthreads();
    for (int base = 0; base < N; base += 1024) {
        int i = base + tid;
        int v = (i < N) ? counts[i] : 0;
#pragma unroll
        for (int off = 1; off < 64; off <<= 1) {
            int t = __shfl_up(v, off, 64);
            if (lane >= off) v += t;
        }
        if (lane == 63) wsum[w] = v;
        __syncthreads();
        if (w == 0) {
            int s = (lane < 16) ? wsum[lane] : 0;
#pragma unroll
            for (int off = 1; off < 16; off <<= 1) {
                int t = __shfl_up(s, off, 64);
                if (lane >= off) s += t;
            }
            if (lane < 16) wsum[lane] = s;
        }
        __syncthreads();
        int waveoff = (w > 0) ? wsum[w - 1] : 0;
        int incl = v + waveoff + s_carry;
        if (i < N) row_ptr[i + 1] = incl;
        __syncthreads();
        if (tid == 1023) s_carry = incl;
        __syncthreads();
    }
}

__global__ void scatter_kernel(const int* __restrict__ ei, const int* __restrict__ row_ptr,
                               int* __restrict__ fill, int* __restrict__ src_sorted, int E) {
    int e = blockIdx.x * blockDim.x + threadIdx.x;
    if (e >= E) return;
    int s = ei[e];
    int d = ei[E + e];
    int pos = row_ptr[d] + atomicAdd(&fill[d], 1);
    src_sorted[pos] = s;
}

// ---------------- fused segment-softmax aggregation + bias + residual + LN ---
// one wave per node; lane l owns elements [4l, 4l+4) of the 256-dim row;
// head h = l >> 3 (8 lanes per head * 4 elems = 32 = HD)
__global__ __launch_bounds__(256) void aggregate_ln(
    const float* __restrict__ xp, const float* __restrict__ x,
    const float* __restrict__ a_src, const float* __restrict__ a_dst,
    const int* __restrict__ row_ptr, const int* __restrict__ src_sorted,
    const float* __restrict__ bias, const float* __restrict__ ln_g,
    const float* __restrict__ ln_b, float* __restrict__ hn, int N) {
    int wave = threadIdx.x >> 6;
    int lane = threadIdx.x & 63;
    int n = blockIdx.x * 4 + wave;
    if (n >= N) return;
    int h = lane >> 3;

    float adst = a_dst[n * H + h];
    // self loop
    float e0 = a_src[n * H + h] + adst;
    e0 = (e0 > 0.f) ? e0 : NEG_SLOPE * e0;
    float ex = __expf(e0);
    float4 xv = *(const float4*)(xp + (size_t)n * DD + lane * 4);
    float acc0 = ex * xv.x, acc1 = ex * xv.y, acc2 = ex * xv.z, acc3 = ex * xv.w;
    float denom = ex;

    int beg = row_ptr[n], end = row_ptr[n + 1];
    for (int i = beg; i < end; i++) {
        int s = src_sorted[i];
        float e = a_src[s * H + h] + adst;
        e = (e > 0.f) ? e : NEG_SLOPE * e;
        float w = __expf(e);
        float4 v = *(const float4*)(xp + (size_t)s * DD + lane * 4);
        acc0 += w * v.x; acc1 += w * v.y; acc2 += w * v.z; acc3 += w * v.w;
        denom += w;
    }
    float inv = 1.f / (denom + 1e-16f);
    float4 bb = *(const float4*)(bias + lane * 4);
    float4 xr = *(const float4*)(x + (size_t)n * DD + lane * 4);
    float r0 = acc0 * inv + bb.x + xr.x;
    float r1 = acc1 * inv + bb.y + xr.y;
    float r2 = acc2 * inv + bb.z + xr.z;
    float r3 = acc3 * inv + bb.w + xr.w;

    // LayerNorm over 256 elems in the wave (two-pass for accuracy)
    float s = r0 + r1 + r2 + r3;
#pragma unroll
    for (int m = 1; m < 64; m <<= 1) s += __shfl_xor(s, m, 64);
    float mu = s * (1.f / 256.f);
    float d0 = r0 - mu, d1 = r1 - mu, d2 = r2 - mu, d3 = r3 - mu;
    float q = d0 * d0 + d1 * d1 + d2 * d2 + d3 * d3;
#pragma unroll
    for (int m = 1; m < 64; m <<= 1) q += __shfl_xor(q, m, 64);
    float rstd = rsqrtf(q * (1.f / 256.f) + 1e-5f);
    float4 g = *(const float4*)(ln_g + lane * 4);
    float4 b = *(const float4*)(ln_b + lane * 4);
    float4 o;
    o.x = d0 * rstd * g.x + b.x;
    o.y = d1 * rstd * g.y + b.y;
    o.z = d2 * rstd * g.z + b.z;
    o.w = d3 * rstd * g.w + b.w;
    *(float4*)(hn + (size_t)n * DD + lane * 4) = o;
}

// ---------------- launch ------------------------------------------------------
extern "C" void kernel_launch(void* const* d_in, const int* in_sizes, int n_in,
                              void* d_out, int out_size, void* d_ws, size_t ws_size,
                              hipStream_t stream) {
    const float* x = (const float*)d_in[0];
    const int* edge_index = (const int*)d_in[1];
    const float* W = (const float*)d_in[3];
    const float* att_src = (const float*)d_in[4];
    const float* att_dst = (const float*)d_in[5];
    const float* bias = (const float*)d_in[6];
    const float* ln_g = (const float*)d_in[7];
    const float* ln_b = (const float*)d_in[8];
    const float* W1 = (const float*)d_in[9];
    const float* b1 = (const float*)d_in[10];
    const float* W2 = (const float*)d_in[11];
    const float* b2 = (const float*)d_in[12];

    const int N = in_sizes[0] / DD;
    const int E = in_sizes[1] / 2;

    // workspace carve-up (floats unless noted)
    float* xp = (float*)d_ws;                    // N*256  (later reused as FFN t1)
    float* hn = xp + (size_t)N * DD;             // N*256
    float* a_src = hn + (size_t)N * DD;          // N*8
    float* a_dst = a_src + (size_t)N * H;        // N*8
    int* row_ptr = (int*)(a_dst + (size_t)N * H);  // N+1
    int* fill = row_ptr + (((N + 1) + 3) & ~3);    // N
    int* src_sorted = fill + ((N + 3) & ~3);       // E

    dim3 gemm_grid((N + TM - 1) / TM, DD / TN);

    // 1. xp = x @ W
    gemm_f32<E_NONE><<<gemm_grid, 256, 0, stream>>>(x, W, nullptr, xp, N, DD, DD);
    // 2. attention scores
    attn_scores<<<(N * H + 255) / 256, 256, 0, stream>>>(xp, att_src, att_dst, a_src, a_dst, N * H);
    // 3. CSR build
    hipMemsetAsync(fill, 0, (size_t)N * sizeof(int), stream);
    hist_kernel<<<(E + 255) / 256, 256, 0, stream>>>(edge_index, fill, E);
    scan_kernel<<<1, 1024, 0, stream>>>(fill, row_ptr, N);
    hipMemsetAsync(fill, 0, (size_t)N * sizeof(int), stream);
    scatter_kernel<<<(E + 255) / 256, 256, 0, stream>>>(edge_index, row_ptr, fill, src_sorted, E);
    // 4. fused softmax-aggregate + bias + residual + LN
    aggregate_ln<<<(N + 3) / 4, 256, 0, stream>>>(xp, x, a_src, a_dst, row_ptr, src_sorted,
                                                  bias, ln_g, ln_b, hn, N);
    // 5. FFN (t1 reuses xp buffer)
    float* t1 = xp;
    gemm_f32<E_BIAS_RELU><<<gemm_grid, 256, 0, stream>>>(hn, W1, b1, t1, N, DD, DD);
    gemm_f32<E_BIAS><<<gemm_grid, 256, 0, stream>>>(t1, W2, b2, (float*)d_out, N, DD, DD);
}

// Round 2
// 416.880 us; speedup vs baseline: 1.8106x; 1.8106x over previous
//
#include <hip/hip_runtime.h>
#include <hip/hip_bf16.h>

#define H 8
#define HD 32
#define DD 256
#define NEG_SLOPE 0.2f

typedef short bf16x8 __attribute__((ext_vector_type(8)));
typedef float f32x4 __attribute__((ext_vector_type(4)));

typedef unsigned short ushort_t;
typedef unsigned int uint_t;

__device__ __forceinline__ unsigned short f2bf(float f) {
    unsigned int u = __float_as_uint(f);
    unsigned int r = (u + 0x7fffu + ((u >> 16) & 1u)) >> 16;
    return (unsigned short)r;
}
__device__ __forceinline__ float bf2f(unsigned short b) {
    return __uint_as_float(((unsigned int)b) << 16);
}

#define GLOAD_LDS16(g, s)                                                        \
    __builtin_amdgcn_global_load_lds((const __attribute__((address_space(1))) void*)(g), \
                                     (__attribute__((address_space(3))) void*)(s), 16, 0, 0)

// ---------------- fp32->bf16 convert for x ----------------------------------
__global__ void conv_x(const float* __restrict__ x, unsigned short* __restrict__ xb, int n4) {
    int i = blockIdx.x * 256 + threadIdx.x;
    if (i >= n4) return;
    float4 v = ((const float4*)x)[i];
    ushort4 o;
    o.x = f2bf(v.x); o.y = f2bf(v.y); o.z = f2bf(v.z); o.w = f2bf(v.w);
    ((ushort4*)xb)[i] = o;
}

// ---------------- W[k][n] fp32 -> Wt[n][k] bf16 ------------------------------
__global__ void conv_wt(const float* __restrict__ W, unsigned short* __restrict__ Wt) {
    int i = blockIdx.x * 256 + threadIdx.x;  // 65536 total
    int n = i >> 8, k = i & 255;
    Wt[i] = f2bf(W[k * 256 + n]);
}

// ---------------- bf16 MFMA GEMM: C[M,256] = A[M,256] @ B, Bt=[n][k] ---------
// block tile 128x128, BK=32, 4 waves (2x2 of 64x64), 16x16x32 bf16 MFMA
enum { E_NONE = 0, E_BIAS_RELU = 1, E_BIAS = 2 };

template <int EPI, bool OBF>
__global__ __launch_bounds__(256) void gemm_bf16(const unsigned short* __restrict__ A,
                                                 const unsigned short* __restrict__ Bt,
                                                 const float* __restrict__ bias,
                                                 void* __restrict__ Cout, int M) {
    constexpr int K = 256;
    __shared__ __align__(16) unsigned short Als[4096];  // [q][m][8] : 4*128*8
    __shared__ __align__(16) unsigned short Bls[4096];  // [q][n][8]

    const int tid = threadIdx.x;
    const int l = tid & 63;
    const int w = tid >> 6;       // wave 0..3
    const int wr = w >> 1, wc = w & 1;
    const int row0 = blockIdx.x * 128;
    const int col0 = blockIdx.y * 128;

    // staging: wave w stages q-group w; instr0 -> m/n = l, instr1 -> m/n = 64+l
    const unsigned short* ga0 = A + (size_t)min(row0 + l, M - 1) * K + w * 8;
    const unsigned short* ga1 = A + (size_t)min(row0 + 64 + l, M - 1) * K + w * 8;
    const unsigned short* gb0 = Bt + (size_t)(col0 + l) * K + w * 8;
    const unsigned short* gb1 = Bt + (size_t)(col0 + 64 + l) * K + w * 8;
    unsigned short* la0 = &Als[(w * 128 + 0) * 8];
    unsigned short* la1 = &Als[(w * 128 + 64) * 8];
    unsigned short* lb0 = &Bls[(w * 128 + 0) * 8];
    unsigned short* lb1 = &Bls[(w * 128 + 64) * 8];

    const int q = l >> 4, r16 = l & 15;

    f32x4 zero = {0.f, 0.f, 0.f, 0.f};
    f32x4 acc[4][4];
#pragma unroll
    for (int i = 0; i < 4; i++)
#pragma unroll
        for (int j = 0; j < 4; j++) acc[i][j] = zero;

    for (int kk = 0; kk < K; kk += 32) {
        GLOAD_LDS16(ga0 + kk, la0);
        GLOAD_LDS16(ga1 + kk, la1);
        GLOAD_LDS16(gb0 + kk, lb0);
        GLOAD_LDS16(gb1 + kk, lb1);
        __syncthreads();
        bf16x8 af[4], bfr[4];
#pragma unroll
        for (int i = 0; i < 4; i++)
            af[i] = *(const bf16x8*)&Als[(q * 128 + wr * 64 + i * 16 + r16) * 8];
#pragma unroll
        for (int j = 0; j < 4; j++)
            bfr[j] = *(const bf16x8*)&Bls[(q * 128 + wc * 64 + j * 16 + r16) * 8];
#pragma unroll
        for (int i = 0; i < 4; i++)
#pragma unroll
            for (int j = 0; j < 4; j++)
                acc[i][j] = __builtin_amdgcn_mfma_f32_16x16x32_bf16(af[i], bfr[j], acc[i][j], 0, 0, 0);
        __syncthreads();
    }

    // epilogue: row=(l>>4)*4+r (+i*16), col=l&15 (+j*16)
    const int orow = row0 + wr * 64 + (l >> 4) * 4;
    const int ocol = col0 + wc * 64 + r16;
#pragma unroll
    for (int i = 0; i < 4; i++) {
#pragma unroll
        for (int r = 0; r < 4; r++) {
            int row = orow + i * 16 + r;
            if (row < M) {
#pragma unroll
                for (int j = 0; j < 4; j++) {
                    int col = ocol + j * 16;
                    float v = acc[i][j][r];
                    if (EPI != E_NONE) v += bias[col];
                    if (EPI == E_BIAS_RELU) v = fmaxf(v, 0.f);
                    if (OBF)
                        ((unsigned short*)Cout)[(size_t)row * 256 + col] = f2bf(v);
                    else
                        ((float*)Cout)[(size_t)row * 256 + col] = v;
                }
            }
        }
    }
}

// ---------------- attention scores from bf16 xp ------------------------------
__global__ void attn_scores(const unsigned short* __restrict__ xp,
                            const float* __restrict__ att_s,
                            const float* __restrict__ att_d,
                            float* __restrict__ a_src, float* __restrict__ a_dst,
                            int NH) {
    int i = blockIdx.x * blockDim.x + threadIdx.x;  // i = n*H + h
    if (i >= NH) return;
    int h = i & (H - 1);
    const uint4* v = (const uint4*)(xp + (size_t)i * HD);
    const float* as = att_s + h * HD;
    const float* ad = att_d + h * HD;
    float s1 = 0.f, s2 = 0.f;
#pragma unroll
    for (int c = 0; c < 4; c++) {  // 4 x uint4 = 32 bf16
        uint4 u = v[c];
        unsigned int ws[4] = {u.x, u.y, u.z, u.w};
#pragma unroll
        for (int p = 0; p < 4; p++) {
            float lo = __uint_as_float(ws[p] << 16);
            float hi = __uint_as_float(ws[p] & 0xffff0000u);
            int base = c * 8 + p * 2;
            s1 += lo * as[base] + hi * as[base + 1];
            s2 += lo * ad[base] + hi * ad[base + 1];
        }
    }
    a_src[i] = s1;
    a_dst[i] = s2;
}

// ---------------- CSR build --------------------------------------------------
__global__ void hist_kernel(const int* __restrict__ ei, int* __restrict__ counts, int E) {
    int e = blockIdx.x * blockDim.x + threadIdx.x;
    if (e < E) atomicAdd(&counts[ei[E + e]], 1);
}

__global__ __launch_bounds__(1024) void scan_block(const int* __restrict__ cnt,
                                                   int* __restrict__ row_ptr,
                                                   int* __restrict__ bsum, int N) {
    __shared__ int ws[16];
    int i = blockIdx.x * 1024 + threadIdx.x;
    int lane = threadIdx.x & 63, w = threadIdx.x >> 6;
    int v = (i < N) ? cnt[i] : 0;
    int sv = v;
#pragma unroll
    for (int off = 1; off < 64; off <<= 1) {
        int t = __shfl_up(sv, off, 64);
        if (lane >= off) sv += t;
    }
    if (lane == 63) ws[w] = sv;
    __syncthreads();
    if (w == 0) {
        int s = (lane < 16) ? ws[lane] : 0;
#pragma unroll
        for (int off = 1; off < 16; off <<= 1) {
            int t = __shfl_up(s, off, 64);
            if (lane >= off) s += t;
        }
        if (lane < 16) ws[lane] = s;
    }
    __syncthreads();
    int incl = sv + ((w > 0) ? ws[w - 1] : 0);
    if (i < N) row_ptr[i + 1] = incl;
    if (threadIdx.x == 1023) bsum[blockIdx.x] = incl;
}

__global__ void scan_partial(int* __restrict__ bsum, int nb) {
    int lane = threadIdx.x;  // 64 threads
    int v = (lane < nb) ? bsum[lane] : 0;
    int s = v;
#pragma unroll
    for (int off = 1; off < 64; off <<= 1) {
        int t = __shfl_up(s, off, 64);
        if (lane >= off) s += t;
    }
    if (lane < nb) bsum[lane] = s - v;  // exclusive
}

__global__ __launch_bounds__(1024) void scan_add(int* __restrict__ row_ptr,
                                                 const int* __restrict__ bsum, int N) {
    int i = blockIdx.x * 1024 + threadIdx.x;
    if (i == 0) row_ptr[0] = 0;
    if (i < N) row_ptr[i + 1] += bsum[blockIdx.x];
}

__global__ void scatter_kernel(const int* __restrict__ ei, const int* __restrict__ row_ptr,
                               int* __restrict__ fill, int* __restrict__ src_sorted, int E) {
    int e = blockIdx.x * blockDim.x + threadIdx.x;
    if (e >= E) return;
    int s = ei[e];
    int d = ei[E + e];
    int pos = row_ptr[d] + atomicAdd(&fill[d], 1);
    src_sorted[pos] = s;
}

// ---------------- fused softmax-aggregate + bias + residual + LN -------------
// one wave per node; lane owns elems [4l,4l+4); head h = l>>3
__global__ __launch_bounds__(256) void aggregate_ln(
    const unsigned short* __restrict__ xp, const float* __restrict__ x,
    const float* __restrict__ a_src, const float* __restrict__ a_dst,
    const int* __restrict__ row_ptr, const int* __restrict__ src_sorted,
    const float* __restrict__ bias, const float* __restrict__ ln_g,
    const float* __restrict__ ln_b, unsigned short* __restrict__ hn, int N) {
    int wave = threadIdx.x >> 6;
    int lane = threadIdx.x & 63;
    int n = blockIdx.x * 4 + wave;
    if (n >= N) return;
    int h = lane >> 3;

    float adst = a_dst[n * H + h];
    float e0 = a_src[n * H + h] + adst;
    e0 = (e0 > 0.f) ? e0 : NEG_SLOPE * e0;
    float ex = __expf(e0);
    ushort4 u = *(const ushort4*)(xp + (size_t)n * DD + lane * 4);
    float acc0 = ex * bf2f(u.x), acc1 = ex * bf2f(u.y);
    float acc2 = ex * bf2f(u.z), acc3 = ex * bf2f(u.w);
    float denom = ex;

    int beg = row_ptr[n], end = row_ptr[n + 1];
    int i = beg;
    for (; i + 1 < end; i += 2) {
        int s0 = src_sorted[i], s1 = src_sorted[i + 1];
        float es0 = a_src[s0 * H + h], es1 = a_src[s1 * H + h];
        ushort4 u0 = *(const ushort4*)(xp + (size_t)s0 * DD + lane * 4);
        ushort4 u1 = *(const ushort4*)(xp + (size_t)s1 * DD + lane * 4);
        float e0a = es0 + adst; e0a = (e0a > 0.f) ? e0a : NEG_SLOPE * e0a;
        float e1a = es1 + adst; e1a = (e1a > 0.f) ? e1a : NEG_SLOPE * e1a;
        float w0 = __expf(e0a), w1 = __expf(e1a);
        acc0 += w0 * bf2f(u0.x) + w1 * bf2f(u1.x);
        acc1 += w0 * bf2f(u0.y) + w1 * bf2f(u1.y);
        acc2 += w0 * bf2f(u0.z) + w1 * bf2f(u1.z);
        acc3 += w0 * bf2f(u0.w) + w1 * bf2f(u1.w);
        denom += w0 + w1;
    }
    if (i < end) {
        int s0 = src_sorted[i];
        float es0 = a_src[s0 * H + h];
        ushort4 u0 = *(const ushort4*)(xp + (size_t)s0 * DD + lane * 4);
        float e0a = es0 + adst; e0a = (e0a > 0.f) ? e0a : NEG_SLOPE * e0a;
        float w0 = __expf(e0a);
        acc0 += w0 * bf2f(u0.x);
        acc1 += w0 * bf2f(u0.y);
        acc2 += w0 * bf2f(u0.z);
        acc3 += w0 * bf2f(u0.w);
        denom += w0;
    }
    float inv = 1.f / (denom + 1e-16f);
    float4 bb = *(const float4*)(bias + lane * 4);
    float4 xr = *(const float4*)(x + (size_t)n * DD + lane * 4);
    float r0 = acc0 * inv + bb.x + xr.x;
    float r1 = acc1 * inv + bb.y + xr.y;
    float r2 = acc2 * inv + bb.z + xr.z;
    float r3 = acc3 * inv + bb.w + xr.w;

    float s = r0 + r1 + r2 + r3;
#pragma unroll
    for (int m = 1; m < 64; m <<= 1) s += __shfl_xor(s, m, 64);
    float mu = s * (1.f / 256.f);
    float d0 = r0 - mu, d1 = r1 - mu, d2 = r2 - mu, d3 = r3 - mu;
    float qv = d0 * d0 + d1 * d1 + d2 * d2 + d3 * d3;
#pragma unroll
    for (int m = 1; m < 64; m <<= 1) qv += __shfl_xor(qv, m, 64);
    float rstd = rsqrtf(qv * (1.f / 256.f) + 1e-5f);
    float4 g = *(const float4*)(ln_g + lane * 4);
    float4 b = *(const float4*)(ln_b + lane * 4);
    ushort4 o;
    o.x = f2bf(d0 * rstd * g.x + b.x);
    o.y = f2bf(d1 * rstd * g.y + b.y);
    o.z = f2bf(d2 * rstd * g.z + b.z);
    o.w = f2bf(d3 * rstd * g.w + b.w);
    *(ushort4*)(hn + (size_t)n * DD + lane * 4) = o;
}

// ---------------- launch ------------------------------------------------------
extern "C" void kernel_launch(void* const* d_in, const int* in_sizes, int n_in,
                              void* d_out, int out_size, void* d_ws, size_t ws_size,
                              hipStream_t stream) {
    const float* x = (const float*)d_in[0];
    const int* edge_index = (const int*)d_in[1];
    const float* W = (const float*)d_in[3];
    const float* att_src = (const float*)d_in[4];
    const float* att_dst = (const float*)d_in[5];
    const float* bias = (const float*)d_in[6];
    const float* ln_g = (const float*)d_in[7];
    const float* ln_b = (const float*)d_in[8];
    const float* W1 = (const float*)d_in[9];
    const float* b1 = (const float*)d_in[10];
    const float* W2 = (const float*)d_in[11];
    const float* b2 = (const float*)d_in[12];

    const int N = in_sizes[0] / DD;
    const int E = in_sizes[1] / 2;

    // workspace carve-up
    char* p = (char*)d_ws;
    auto carve = [&](size_t bytes) {
        char* r = p;
        p += (bytes + 255) & ~(size_t)255;
        return r;
    };
    unsigned short* x_bf = (unsigned short*)carve((size_t)N * DD * 2);
    unsigned short* xp_bf = (unsigned short*)carve((size_t)N * DD * 2);
    unsigned short* hn_bf = (unsigned short*)carve((size_t)N * DD * 2);
    float* a_src = (float*)carve((size_t)N * H * 4);
    float* a_dst = (float*)carve((size_t)N * H * 4);
    int* row_ptr = (int*)carve((size_t)(N + 1) * 4);
    int* cnt = (int*)carve((size_t)N * 4);
    int* fill = (int*)carve((size_t)N * 4);
    int* bsum = (int*)carve(256 * 4);
    int* src_sorted = (int*)carve((size_t)E * 4);
    unsigned short* Wt = (unsigned short*)carve(65536 * 2);
    unsigned short* W1t = (unsigned short*)carve(65536 * 2);
    unsigned short* W2t = (unsigned short*)carve(65536 * 2);
    unsigned short* t1_bf = x_bf;  // reuse after GEMM1

    // prep: conversions
    conv_x<<<(N * DD / 4 + 255) / 256, 256, 0, stream>>>(x, x_bf, N * DD / 4);
    conv_wt<<<256, 256, 0, stream>>>(W, Wt);
    conv_wt<<<256, 256, 0, stream>>>(W1, W1t);
    conv_wt<<<256, 256, 0, stream>>>(W2, W2t);

    dim3 ggrid((N + 127) / 128, 2);

    // 1. xp = x @ W  (bf16 out)
    gemm_bf16<E_NONE, true><<<ggrid, 256, 0, stream>>>(x_bf, Wt, nullptr, xp_bf, N);
    // 2. attention scores
    attn_scores<<<(N * H + 255) / 256, 256, 0, stream>>>(xp_bf, att_src, att_dst, a_src, a_dst, N * H);
    // 3. CSR build
    hipMemsetAsync(cnt, 0, (size_t)N * sizeof(int), stream);
    hist_kernel<<<(E + 255) / 256, 256, 0, stream>>>(edge_index, cnt, E);
    int nb = (N + 1023) / 1024;
    scan_block<<<nb, 1024, 0, stream>>>(cnt, row_ptr, bsum, N);
    scan_partial<<<1, 64, 0, stream>>>(bsum, nb);
    scan_add<<<nb, 1024, 0, stream>>>(row_ptr, bsum, N);
    hipMemsetAsync(fill, 0, (size_t)N * sizeof(int), stream);
    scatter_kernel<<<(E + 255) / 256, 256, 0, stream>>>(edge_index, row_ptr, fill, src_sorted, E);
    // 4. fused aggregate + LN (bf16 out)
    aggregate_ln<<<(N + 3) / 4, 256, 0, stream>>>(xp_bf, x, a_src, a_dst, row_ptr, src_sorted,
                                                  bias, ln_g, ln_b, hn_bf, N);
    // 5. FFN
    gemm_bf16<E_BIAS_RELU, true><<<ggrid, 256, 0, stream>>>(hn_bf, W1t, b1, t1_bf, N);
    gemm_bf16<E_BIAS, false><<<ggrid, 256, 0, stream>>>(t1_bf, W2t, b2, d_out, N);
}